// Round 9
// baseline (282.812 us; speedup 1.0000x reference)
//
#include <hip/hip_runtime.h>

typedef unsigned short ushort_t;
typedef __attribute__((ext_vector_type(8))) short short8;
typedef __attribute__((ext_vector_type(4))) float f32x4;

#define MFMA_BF16(a, b, c) __builtin_amdgcn_mfma_f32_16x16x32_bf16((a), (b), (c), 0, 0, 0)

#define T_LEN 1024
#define BATCH 4
#define NHEAD 16
#define DHEAD 64
#define EMB 1024

__device__ __forceinline__ ushort_t f2bf(float f) {
  unsigned u = __float_as_uint(f);
  u += 0x7fffu + ((u >> 16) & 1u);
  return (ushort_t)(u >> 16);
}

// ---------------- elementwise ----------------
__global__ void sample_bf16_kernel(const float* __restrict__ mu, const float* __restrict__ rho,
                                   const float* __restrict__ eps, ushort_t* __restrict__ out, int n) {
  int i = blockIdx.x * 256 + threadIdx.x;
  if (i < n) {
    float sp = log1pf(__expf(rho[i]));
    out[i] = f2bf(mu[i] + sp * eps[i]);
  }
}

__global__ void sample_f32_kernel(const float* __restrict__ mu, const float* __restrict__ rho,
                                  const float* __restrict__ eps, float* __restrict__ out, int n) {
  int i = blockIdx.x * 256 + threadIdx.x;
  if (i < n) {
    float sp = log1pf(__expf(rho[i]));
    out[i] = mu[i] + sp * eps[i];
  }
}

__global__ void cast_bf16_kernel(const float* __restrict__ in, ushort_t* __restrict__ out, int n) {
  int i = blockIdx.x * 256 + threadIdx.x;
  if (i < n) out[i] = f2bf(in[i]);
}

// zero the rhp pad rows (phys rows 0..63 and 1088..1151 per head)
__global__ void zero_rhp_pad_kernel(ushort_t* __restrict__ rhp) {
  int idx = blockIdx.x * 256 + threadIdx.x;   // 16*128*64 = 131072
  int dd = idx & 63;
  int pr = (idx >> 6) & 127;
  int h = idx >> 13;
  int phys = (pr < 64) ? pr : (pr - 64 + 1088);
  rhp[((size_t)h * 1152 + phys) * 64 + dd] = 0;
}

// ---------------- GEMM: C[M][N] = A[M][K] * Bt[N][K]^T + bias[N] (f32 out) ----------------
__global__ __launch_bounds__(256, 2)
void gemm_bt_kernel(const ushort_t* __restrict__ A, const ushort_t* __restrict__ Bt,
                    const float* __restrict__ bias, float* __restrict__ C,
                    int M, int N, int K) {
  __shared__ ushort_t As[128 * 32];
  __shared__ ushort_t Bs[128 * 32];
  const int tid = threadIdx.x;
  const int w = tid >> 6, l = tid & 63;
  const int m0 = blockIdx.x * 128, n0 = blockIdx.y * 128;
  const int wr = w >> 1, wc = w & 1;
  const int fr = l & 15, fk = (l >> 4) * 8;

  f32x4 acc[4][4] = {};

  for (int k0 = 0; k0 < K; k0 += 32) {
    __syncthreads();
#pragma unroll
    for (int p = 0; p < 2; ++p) {
      int c = p * 256 + tid;
      int row = c >> 2, col = (c & 3) * 8;
      *(short8*)(&As[c * 8]) = *(const short8*)(&A[(size_t)(m0 + row) * K + k0 + col]);
      *(short8*)(&Bs[c * 8]) = *(const short8*)(&Bt[(size_t)(n0 + row) * K + k0 + col]);
    }
    __syncthreads();
    short8 af[4], bf[4];
#pragma unroll
    for (int mi = 0; mi < 4; ++mi) af[mi] = *(const short8*)(&As[(wr * 64 + mi * 16 + fr) * 32 + fk]);
#pragma unroll
    for (int ni = 0; ni < 4; ++ni) bf[ni] = *(const short8*)(&Bs[(wc * 64 + ni * 16 + fr) * 32 + fk]);
#pragma unroll
    for (int mi = 0; mi < 4; ++mi)
#pragma unroll
      for (int ni = 0; ni < 4; ++ni)
        acc[mi][ni] = MFMA_BF16(af[mi], bf[ni], acc[mi][ni]);
  }

#pragma unroll
  for (int ni = 0; ni < 4; ++ni) {
    int col = n0 + wc * 64 + ni * 16 + fr;
    float bv = bias[col];
#pragma unroll
    for (int mi = 0; mi < 4; ++mi) {
#pragma unroll
      for (int q = 0; q < 4; ++q) {
        int row = m0 + wr * 64 + mi * 16 + (l >> 4) * 4 + q;
        C[(size_t)row * N + col] = acc[mi][ni][q] + bv;
      }
    }
  }
}

// ---------------- fused QKV GEMM: epilogue writes qrw/qrr/kb/vt directly ----------------
__global__ __launch_bounds__(256, 2)
void gemm_qkv_fused_kernel(const ushort_t* __restrict__ A, const ushort_t* __restrict__ Bt,
                           const float* __restrict__ bias,
                           const float* __restrict__ rwb, const float* __restrict__ rrb,
                           ushort_t* __restrict__ qrw, ushort_t* __restrict__ qrr,
                           ushort_t* __restrict__ kbuf, ushort_t* __restrict__ vt) {
  __shared__ ushort_t As[128 * 32];
  __shared__ ushort_t Bs[128 * 32];
  const int K = 1024;
  const int tid = threadIdx.x;
  const int w = tid >> 6, l = tid & 63;
  const int m0 = blockIdx.x * 128, n0 = blockIdx.y * 128;
  const int wr = w >> 1, wc = w & 1;
  const int fr = l & 15, fk = (l >> 4) * 8;

  f32x4 acc[4][4] = {};

  for (int k0 = 0; k0 < K; k0 += 32) {
    __syncthreads();
#pragma unroll
    for (int p = 0; p < 2; ++p) {
      int c = p * 256 + tid;
      int row = c >> 2, col = (c & 3) * 8;
      *(short8*)(&As[c * 8]) = *(const short8*)(&A[(size_t)(m0 + row) * K + k0 + col]);
      *(short8*)(&Bs[c * 8]) = *(const short8*)(&Bt[(size_t)(n0 + row) * K + k0 + col]);
    }
    __syncthreads();
    short8 af[4], bf[4];
#pragma unroll
    for (int mi = 0; mi < 4; ++mi) af[mi] = *(const short8*)(&As[(wr * 64 + mi * 16 + fr) * 32 + fk]);
#pragma unroll
    for (int ni = 0; ni < 4; ++ni) bf[ni] = *(const short8*)(&Bs[(wc * 64 + ni * 16 + fr) * 32 + fk]);
#pragma unroll
    for (int mi = 0; mi < 4; ++mi)
#pragma unroll
      for (int ni = 0; ni < 4; ++ni)
        acc[mi][ni] = MFMA_BF16(af[mi], bf[ni], acc[mi][ni]);
  }

#pragma unroll
  for (int ni = 0; ni < 4; ++ni) {
    int col = n0 + wc * 64 + ni * 16 + fr;
    int part = col >> 10;
    int e = col & 1023;
    int hh = e >> 6, dd = e & 63;
    float bv = bias[col];
    float rwv = rwb[e];
    float rrv = rrb[e];
#pragma unroll
    for (int mi = 0; mi < 4; ++mi) {
#pragma unroll
      for (int q = 0; q < 4; ++q) {
        int row = m0 + wr * 64 + mi * 16 + (l >> 4) * 4 + q;
        int t = row >> 2, b = row & 3;
        float v = acc[mi][ni][q] + bv;
        if (part == 0) {
          unsigned idx = (((unsigned)(b * 16 + hh) * 1024 + t) << 6) + dd;
          qrw[idx] = f2bf(v + rwv);
          qrr[idx] = f2bf(v + rrv);
        } else if (part == 1) {
          unsigned idx = (((unsigned)(b * 16 + hh) * 1024 + t) << 6) + dd;
          kbuf[idx] = f2bf(v);
        } else {
          vt[(((unsigned)(b * 16 + hh) * 64 + dd) << 10) + t] = f2bf(v);
        }
      }
    }
  }
}

// ---------------- fused pos GEMM: epilogue writes rhp[h][64+t][dd] directly ----------------
__global__ __launch_bounds__(256, 2)
void gemm_pos_fused_kernel(const ushort_t* __restrict__ A, const ushort_t* __restrict__ Bt,
                           const float* __restrict__ bias, ushort_t* __restrict__ rhp) {
  __shared__ ushort_t As[128 * 32];
  __shared__ ushort_t Bs[128 * 32];
  const int K = 1024;
  const int tid = threadIdx.x;
  const int w = tid >> 6, l = tid & 63;
  const int m0 = blockIdx.x * 128, n0 = blockIdx.y * 128;
  const int wr = w >> 1, wc = w & 1;
  const int fr = l & 15, fk = (l >> 4) * 8;

  f32x4 acc[4][4] = {};

  for (int k0 = 0; k0 < K; k0 += 32) {
    __syncthreads();
#pragma unroll
    for (int p = 0; p < 2; ++p) {
      int c = p * 256 + tid;
      int row = c >> 2, col = (c & 3) * 8;
      *(short8*)(&As[c * 8]) = *(const short8*)(&A[(size_t)(m0 + row) * K + k0 + col]);
      *(short8*)(&Bs[c * 8]) = *(const short8*)(&Bt[(size_t)(n0 + row) * K + k0 + col]);
    }
    __syncthreads();
    short8 af[4], bf[4];
#pragma unroll
    for (int mi = 0; mi < 4; ++mi) af[mi] = *(const short8*)(&As[(wr * 64 + mi * 16 + fr) * 32 + fk]);
#pragma unroll
    for (int ni = 0; ni < 4; ++ni) bf[ni] = *(const short8*)(&Bs[(wc * 64 + ni * 16 + fr) * 32 + fk]);
#pragma unroll
    for (int mi = 0; mi < 4; ++mi)
#pragma unroll
      for (int ni = 0; ni < 4; ++ni)
        acc[mi][ni] = MFMA_BF16(af[mi], bf[ni], acc[mi][ni]);
  }

#pragma unroll
  for (int ni = 0; ni < 4; ++ni) {
    int col = n0 + wc * 64 + ni * 16 + fr;
    int hh = col >> 6, dd = col & 63;
    float bv = bias[col];
#pragma unroll
    for (int mi = 0; mi < 4; ++mi) {
#pragma unroll
      for (int q = 0; q < 4; ++q) {
        int t = m0 + wr * 64 + mi * 16 + (l >> 4) * 4 + q;
        rhp[((unsigned)hh * 1152 + 64 + t) * 64 + dd] = f2bf(acc[mi][ni][q] + bv);
      }
    }
  }
}

// ---------------- fused rel-shift attention v4: static-max softmax + K/R prefetch ----------------
// Static max (SMAX=20): P = exp(s-20). exp(m-20) cancels in o/s exactly, so no per-tile
// row-max shuffle-reduce, no m_run, no O rescale; s_run accumulates per-lane, reduced once
// in the epilogue. Safe: s ~ N(0,~2), f32 exp fine for s-20 in [-120, 88].
// 2-stage software pipeline: next tile's 18 K/R loads issue before current tile's compute
// (named A/B register sets; no barriers -> compiler emits counted vmcnt, loads stay in flight).
#define LOADKR(KF, RF, J0)                                            \
  do {                                                                \
    unsigned koff = kbase + (unsigned)(J0) * 64;                      \
    _Pragma("unroll")                                                 \
    for (int f = 0; f < 4; ++f) {                                     \
      KF[2 * f]     = *(const short8*)(kb + koff + f * 1024);         \
      KF[2 * f + 1] = *(const short8*)(kb + koff + f * 1024 + 32);    \
    }                                                                 \
    unsigned roff = rbase + (unsigned)(J0) * 64;                      \
    _Pragma("unroll")                                                 \
    for (int f = 0; f < 5; ++f) {                                     \
      RF[2 * f]     = *(const short8*)(rhp + roff + f * 1024);        \
      RF[2 * f + 1] = *(const short8*)(rhp + roff + f * 1024 + 32);   \
    }                                                                 \
  } while (0)

#define TILE(KF, RF, J0)                                              \
  do {                                                                \
    f32x4 ac[4] = {};                                                 \
    f32x4 pb[5] = {};                                                 \
    _Pragma("unroll")                                                 \
    for (int f = 0; f < 4; ++f) {                                     \
      ac[f] = MFMA_BF16(aqw0, KF[2 * f], ac[f]);                      \
      ac[f] = MFMA_BF16(aqw1, KF[2 * f + 1], ac[f]);                  \
    }                                                                 \
    _Pragma("unroll")                                                 \
    for (int f = 0; f < 5; ++f) {                                     \
      pb[f] = MFMA_BF16(aqr0, RF[2 * f], pb[f]);                      \
      pb[f] = MFMA_BF16(aqr1, RF[2 * f + 1], pb[f]);                  \
    }                                                                 \
    _Pragma("unroll")                                                 \
    for (int q = 0; q < 4; ++q) {                                     \
      int ri = 4 * (l >> 4) + q;                                      \
      int e = 15 + fr - ri;                                           \
      int src = (l & 48) | (e & 15);                                  \
      float sh[5];                                                    \
      _Pragma("unroll")                                               \
      for (int f = 0; f < 5; ++f) sh[f] = __shfl(pb[f][q], src, 64);  \
      int hi = e >> 4;                                                \
      int ig = istrip + ri;                                           \
      _Pragma("unroll")                                               \
      for (int ni = 0; ni < 4; ++ni) {                                \
        float pv = hi ? sh[ni + 1] : sh[ni];                          \
        float s = (ac[ni][q] + pv) * scale - 20.0f;                   \
        int jg = (J0) + ni * 16 + fr;                                 \
        float p = (jg > ig) ? 0.f : __expf(s);                        \
        *(ushort_t*)(Pw + (((ri * 128) + (ni * 16 + fr) * 2) ^ ((ri & 7) << 4))) = f2bf(p); \
        s_run[q] += p;                                                \
      }                                                               \
    }                                                                 \
    short8 pa0 = *(const short8*)(Pw + ((fr * 128 + fkq * 2) ^ ((fr & 7) << 4)));      \
    short8 pa1 = *(const short8*)(Pw + ((fr * 128 + 64 + fkq * 2) ^ ((fr & 7) << 4))); \
    short8 vf[8];                                                     \
    _Pragma("unroll")                                                 \
    for (int dg = 0; dg < 4; ++dg) {                                  \
      unsigned vb = vbase + (unsigned)(dg * 16384) + (unsigned)(J0);  \
      vf[2 * dg]     = *(const short8*)(vt + vb);                     \
      vf[2 * dg + 1] = *(const short8*)(vt + vb + 32);                \
    }                                                                 \
    _Pragma("unroll")                                                 \
    for (int dg = 0; dg < 4; ++dg) {                                  \
      o[dg] = MFMA_BF16(pa0, vf[2 * dg], o[dg]);                      \
      o[dg] = MFMA_BF16(pa1, vf[2 * dg + 1], o[dg]);                  \
    }                                                                 \
  } while (0)

__global__ __launch_bounds__(256, 2)
void attn_kernel(const ushort_t* __restrict__ qrw, const ushort_t* __restrict__ qrr,
                 const ushort_t* __restrict__ kb, const ushort_t* __restrict__ vt,
                 const ushort_t* __restrict__ rhp, ushort_t* __restrict__ ctx) {
  __shared__ __attribute__((aligned(16))) char PtB[4][2048];  // [16][64] bf16 per wave, swizzled

  const int tid = threadIdx.x, w = tid >> 6, l = tid & 63;
  const int bid = blockIdx.x;
  const int g = bid & 63;
  const int h = ((g & 7) << 1) | ((g >> 3) & 1);   // bid%8 fixes the head-pair (XCD L2 locality)
  const int b = g >> 4;
  const int bh = b * 16 + h;
  const int sx = 15 - (bid >> 6);                  // reversed: big strips first
  const int istrip = sx * 64 + w * 16;             // this wave's 16 q-rows
  const int fr = l & 15, fkq = (l >> 4) * 8;
  const float scale = 0.125f;
  char* Pw = PtB[w];

  // Q fragments in registers for the whole loop
  short8 aqw0, aqw1, aqr0, aqr1;
  {
    unsigned qb = ((unsigned)bh * T_LEN + istrip + fr) * 64 + fkq;
    aqw0 = *(const short8*)(qrw + qb);
    aqw1 = *(const short8*)(qrw + qb + 32);
    aqr0 = *(const short8*)(qrr + qb);
    aqr1 = *(const short8*)(qrr + qb + 32);
  }

  const unsigned kbase = ((unsigned)bh * T_LEN + fr) * 64 + fkq;
  const unsigned rbase = ((unsigned)h * 1152 + 64 + 1008 - istrip + fr) * 64 + fkq;
  const unsigned vbase = ((unsigned)bh * 64 + fr) * T_LEN + fkq;

  float s_run[4] = {0.f, 0.f, 0.f, 0.f};
  f32x4 o[4] = {};                                 // [d-group][q]

  const int njt = (istrip + 79) >> 6;              // 64-col tiles (per-wave causal bound)

  short8 kA[8], rA[10], kB[8], rB[10];
  LOADKR(kA, rA, 0);
  int jt = 0;
  for (;;) {
    if (jt + 1 < njt) LOADKR(kB, rB, (jt + 1) << 6);
    TILE(kA, rA, jt << 6);
    ++jt;
    if (jt == njt) break;
    if (jt + 1 < njt) LOADKR(kA, rA, (jt + 1) << 6);
    TILE(kB, rB, jt << 6);
    ++jt;
    if (jt == njt) break;
  }

  // ---- epilogue: one-time row-sum reduce, normalize, write ctx [T][B][E] bf16 ----
#pragma unroll
  for (int q = 0; q < 4; ++q) {
    float sq = s_run[q];
#pragma unroll
    for (int o2 = 8; o2; o2 >>= 1) sq += __shfl_xor(sq, o2, 64);
    s_run[q] = sq;
  }
#pragma unroll
  for (int dg = 0; dg < 4; ++dg) {
#pragma unroll
    for (int q = 0; q < 4; ++q) {
      int ig = istrip + 4 * (l >> 4) + q;
      int dd = dg * 16 + fr;
      float val = o[dg][q] / s_run[q];
      ctx[((size_t)ig * BATCH + b) * EMB + h * 64 + dd] = f2bf(val);
    }
  }
}

// ---------------- launch ----------------
extern "C" void kernel_launch(void* const* d_in, const int* in_sizes, int n_in,
                              void* d_out, int out_size, void* d_ws, size_t ws_size,
                              hipStream_t stream) {
  (void)in_sizes; (void)n_in; (void)out_size; (void)ws_size;
  const float* x = (const float*)d_in[0];
  const float* pos = (const float*)d_in[1];
  const float* in_w_mu = (const float*)d_in[3];
  const float* in_w_rho = (const float*)d_in[4];
  const float* in_w_eps = (const float*)d_in[5];
  const float* in_b_mu = (const float*)d_in[6];
  const float* in_b_rho = (const float*)d_in[7];
  const float* in_b_eps = (const float*)d_in[8];
  const float* pos_w_mu = (const float*)d_in[9];
  const float* pos_w_rho = (const float*)d_in[10];
  const float* pos_w_eps = (const float*)d_in[11];
  const float* pos_b_mu = (const float*)d_in[12];
  const float* pos_b_rho = (const float*)d_in[13];
  const float* pos_b_eps = (const float*)d_in[14];
  const float* out_w_mu = (const float*)d_in[15];
  const float* out_w_rho = (const float*)d_in[16];
  const float* out_w_eps = (const float*)d_in[17];
  const float* out_b_mu = (const float*)d_in[18];
  const float* out_b_rho = (const float*)d_in[19];
  const float* out_b_eps = (const float*)d_in[20];
  const float* rw_mu = (const float*)d_in[21];
  const float* rw_rho = (const float*)d_in[22];
  const float* rw_eps = (const float*)d_in[23];
  const float* rr_mu = (const float*)d_in[24];
  const float* rr_rho = (const float*)d_in[25];
  const float* rr_eps = (const float*)d_in[26];

  char* ws = (char*)d_ws;
  ushort_t* in_w_bf  = (ushort_t*)(ws + 0);          // 3072x1024 bf16
  ushort_t* pos_w_bf = (ushort_t*)(ws + 6291456);    // 1024x1024 bf16
  ushort_t* out_w_bf = (ushort_t*)(ws + 8388608);    // 1024x1024 bf16
  float* in_b  = (float*)(ws + 10485760);            // 3072
  float* pos_b = (float*)(ws + 10498048);            // 1024
  float* out_b = (float*)(ws + 10502144);            // 1024
  float* rwb   = (float*)(ws + 10506240);            // 1024
  float* rrb   = (float*)(ws + 10510336);            // 1024
  ushort_t* x_bf    = (ushort_t*)(ws + 10514432);    // 4096x1024 bf16
  ushort_t* posx_bf = (ushort_t*)(ws + 18903040);    // 1024x1024 bf16
  ushort_t* qrw = (ushort_t*)(ws + 21000192);        // [B][H][T][64] bf16
  ushort_t* qrr = (ushort_t*)(ws + 29388800);
  ushort_t* kb  = (ushort_t*)(ws + 37777408);
  ushort_t* vt  = (ushort_t*)(ws + 46166016);        // [B][H][64][T] bf16
  ushort_t* rhp = (ushort_t*)(ws + 54554624);        // [H][1152][64] bf16
  ushort_t* ctx = (ushort_t*)(ws + 56913920);        // [T][B][E] bf16

  sample_bf16_kernel<<<12288, 256, 0, stream>>>(in_w_mu, in_w_rho, in_w_eps, in_w_bf, 3145728);
  sample_bf16_kernel<<<4096, 256, 0, stream>>>(pos_w_mu, pos_w_rho, pos_w_eps, pos_w_bf, 1048576);
  sample_bf16_kernel<<<4096, 256, 0, stream>>>(out_w_mu, out_w_rho, out_w_eps, out_w_bf, 1048576);
  sample_f32_kernel<<<12, 256, 0, stream>>>(in_b_mu, in_b_rho, in_b_eps, in_b, 3072);
  sample_f32_kernel<<<4, 256, 0, stream>>>(pos_b_mu, pos_b_rho, pos_b_eps, pos_b, 1024);
  sample_f32_kernel<<<4, 256, 0, stream>>>(out_b_mu, out_b_rho, out_b_eps, out_b, 1024);
  sample_f32_kernel<<<4, 256, 0, stream>>>(rw_mu, rw_rho, rw_eps, rwb, 1024);
  sample_f32_kernel<<<4, 256, 0, stream>>>(rr_mu, rr_rho, rr_eps, rrb, 1024);
  cast_bf16_kernel<<<16384, 256, 0, stream>>>(x, x_bf, 4194304);
  cast_bf16_kernel<<<4096, 256, 0, stream>>>(pos, posx_bf, 1048576);
  zero_rhp_pad_kernel<<<512, 256, 0, stream>>>(rhp);

  gemm_qkv_fused_kernel<<<dim3(32, 24), 256, 0, stream>>>(x_bf, in_w_bf, in_b, rwb, rrb,
                                                          qrw, qrr, kb, vt);
  gemm_pos_fused_kernel<<<dim3(8, 8), 256, 0, stream>>>(posx_bf, pos_w_bf, pos_b, rhp);

  attn_kernel<<<dim3(1024), 256, 0, stream>>>(qrw, qrr, kb, vt, rhp, ctx);

  gemm_bt_kernel<<<dim3(32, 8), 256, 0, stream>>>(ctx, out_w_bf, out_b, (float*)d_out, 4096, 1024, 1024);
}

// Round 10
// 274.304 us; speedup vs baseline: 1.0310x; 1.0310x over previous
//
#include <hip/hip_runtime.h>

typedef unsigned short ushort_t;
typedef __attribute__((ext_vector_type(8))) short short8;
typedef __attribute__((ext_vector_type(4))) float f32x4;

#define MFMA_BF16(a, b, c) __builtin_amdgcn_mfma_f32_16x16x32_bf16((a), (b), (c), 0, 0, 0)

#define T_LEN 1024
#define BATCH 4
#define NHEAD 16
#define DHEAD 64
#define EMB 1024

__device__ __forceinline__ ushort_t f2bf(float f) {
  unsigned u = __float_as_uint(f);
  u += 0x7fffu + ((u >> 16) & 1u);
  return (ushort_t)(u >> 16);
}

// ---------------- elementwise ----------------
__global__ void sample_bf16_kernel(const float* __restrict__ mu, const float* __restrict__ rho,
                                   const float* __restrict__ eps, ushort_t* __restrict__ out, int n) {
  int i = blockIdx.x * 256 + threadIdx.x;
  if (i < n) {
    float sp = log1pf(__expf(rho[i]));
    out[i] = f2bf(mu[i] + sp * eps[i]);
  }
}

__global__ void sample_f32_kernel(const float* __restrict__ mu, const float* __restrict__ rho,
                                  const float* __restrict__ eps, float* __restrict__ out, int n) {
  int i = blockIdx.x * 256 + threadIdx.x;
  if (i < n) {
    float sp = log1pf(__expf(rho[i]));
    out[i] = mu[i] + sp * eps[i];
  }
}

__global__ void cast_bf16_kernel(const float* __restrict__ in, ushort_t* __restrict__ out, int n) {
  int i = blockIdx.x * 256 + threadIdx.x;
  if (i < n) out[i] = f2bf(in[i]);
}

// zero the rhp pad rows (phys rows 0..63 and 1088..1151 per head)
__global__ void zero_rhp_pad_kernel(ushort_t* __restrict__ rhp) {
  int idx = blockIdx.x * 256 + threadIdx.x;   // 16*128*64 = 131072
  int dd = idx & 63;
  int pr = (idx >> 6) & 127;
  int h = idx >> 13;
  int phys = (pr < 64) ? pr : (pr - 64 + 1088);
  rhp[((size_t)h * 1152 + phys) * 64 + dd] = 0;
}

// ---------------- GEMM: C[M][N] = A[M][K] * Bt[N][K]^T + bias[N] (f32 out) ----------------
__global__ __launch_bounds__(256, 2)
void gemm_bt_kernel(const ushort_t* __restrict__ A, const ushort_t* __restrict__ Bt,
                    const float* __restrict__ bias, float* __restrict__ C,
                    int M, int N, int K) {
  __shared__ ushort_t As[128 * 32];
  __shared__ ushort_t Bs[128 * 32];
  const int tid = threadIdx.x;
  const int w = tid >> 6, l = tid & 63;
  const int m0 = blockIdx.x * 128, n0 = blockIdx.y * 128;
  const int wr = w >> 1, wc = w & 1;
  const int fr = l & 15, fk = (l >> 4) * 8;

  f32x4 acc[4][4] = {};

  for (int k0 = 0; k0 < K; k0 += 32) {
    __syncthreads();
#pragma unroll
    for (int p = 0; p < 2; ++p) {
      int c = p * 256 + tid;
      int row = c >> 2, col = (c & 3) * 8;
      *(short8*)(&As[c * 8]) = *(const short8*)(&A[(size_t)(m0 + row) * K + k0 + col]);
      *(short8*)(&Bs[c * 8]) = *(const short8*)(&Bt[(size_t)(n0 + row) * K + k0 + col]);
    }
    __syncthreads();
    short8 af[4], bf[4];
#pragma unroll
    for (int mi = 0; mi < 4; ++mi) af[mi] = *(const short8*)(&As[(wr * 64 + mi * 16 + fr) * 32 + fk]);
#pragma unroll
    for (int ni = 0; ni < 4; ++ni) bf[ni] = *(const short8*)(&Bs[(wc * 64 + ni * 16 + fr) * 32 + fk]);
#pragma unroll
    for (int mi = 0; mi < 4; ++mi)
#pragma unroll
      for (int ni = 0; ni < 4; ++ni)
        acc[mi][ni] = MFMA_BF16(af[mi], bf[ni], acc[mi][ni]);
  }

#pragma unroll
  for (int ni = 0; ni < 4; ++ni) {
    int col = n0 + wc * 64 + ni * 16 + fr;
    float bv = bias[col];
#pragma unroll
    for (int mi = 0; mi < 4; ++mi) {
#pragma unroll
      for (int q = 0; q < 4; ++q) {
        int row = m0 + wr * 64 + mi * 16 + (l >> 4) * 4 + q;
        C[(size_t)row * N + col] = acc[mi][ni][q] + bv;
      }
    }
  }
}

// ---------------- fused QKV GEMM: epilogue writes qrw/qrr/kb/vt directly ----------------
__global__ __launch_bounds__(256, 2)
void gemm_qkv_fused_kernel(const ushort_t* __restrict__ A, const ushort_t* __restrict__ Bt,
                           const float* __restrict__ bias,
                           const float* __restrict__ rwb, const float* __restrict__ rrb,
                           ushort_t* __restrict__ qrw, ushort_t* __restrict__ qrr,
                           ushort_t* __restrict__ kbuf, ushort_t* __restrict__ vt) {
  __shared__ ushort_t As[128 * 32];
  __shared__ ushort_t Bs[128 * 32];
  const int K = 1024;
  const int tid = threadIdx.x;
  const int w = tid >> 6, l = tid & 63;
  const int m0 = blockIdx.x * 128, n0 = blockIdx.y * 128;
  const int wr = w >> 1, wc = w & 1;
  const int fr = l & 15, fk = (l >> 4) * 8;

  f32x4 acc[4][4] = {};

  for (int k0 = 0; k0 < K; k0 += 32) {
    __syncthreads();
#pragma unroll
    for (int p = 0; p < 2; ++p) {
      int c = p * 256 + tid;
      int row = c >> 2, col = (c & 3) * 8;
      *(short8*)(&As[c * 8]) = *(const short8*)(&A[(size_t)(m0 + row) * K + k0 + col]);
      *(short8*)(&Bs[c * 8]) = *(const short8*)(&Bt[(size_t)(n0 + row) * K + k0 + col]);
    }
    __syncthreads();
    short8 af[4], bf[4];
#pragma unroll
    for (int mi = 0; mi < 4; ++mi) af[mi] = *(const short8*)(&As[(wr * 64 + mi * 16 + fr) * 32 + fk]);
#pragma unroll
    for (int ni = 0; ni < 4; ++ni) bf[ni] = *(const short8*)(&Bs[(wc * 64 + ni * 16 + fr) * 32 + fk]);
#pragma unroll
    for (int mi = 0; mi < 4; ++mi)
#pragma unroll
      for (int ni = 0; ni < 4; ++ni)
        acc[mi][ni] = MFMA_BF16(af[mi], bf[ni], acc[mi][ni]);
  }

#pragma unroll
  for (int ni = 0; ni < 4; ++ni) {
    int col = n0 + wc * 64 + ni * 16 + fr;
    int part = col >> 10;
    int e = col & 1023;
    int hh = e >> 6, dd = e & 63;
    float bv = bias[col];
    float rwv = rwb[e];
    float rrv = rrb[e];
#pragma unroll
    for (int mi = 0; mi < 4; ++mi) {
#pragma unroll
      for (int q = 0; q < 4; ++q) {
        int row = m0 + wr * 64 + mi * 16 + (l >> 4) * 4 + q;
        int t = row >> 2, b = row & 3;
        float v = acc[mi][ni][q] + bv;
        if (part == 0) {
          unsigned idx = (((unsigned)(b * 16 + hh) * 1024 + t) << 6) + dd;
          qrw[idx] = f2bf(v + rwv);
          qrr[idx] = f2bf(v + rrv);
        } else if (part == 1) {
          unsigned idx = (((unsigned)(b * 16 + hh) * 1024 + t) << 6) + dd;
          kbuf[idx] = f2bf(v);
        } else {
          vt[(((unsigned)(b * 16 + hh) * 64 + dd) << 10) + t] = f2bf(v);
        }
      }
    }
  }
}

// ---------------- fused pos GEMM: epilogue writes rhp[h][64+t][dd] directly ----------------
__global__ __launch_bounds__(256, 2)
void gemm_pos_fused_kernel(const ushort_t* __restrict__ A, const ushort_t* __restrict__ Bt,
                           const float* __restrict__ bias, ushort_t* __restrict__ rhp) {
  __shared__ ushort_t As[128 * 32];
  __shared__ ushort_t Bs[128 * 32];
  const int K = 1024;
  const int tid = threadIdx.x;
  const int w = tid >> 6, l = tid & 63;
  const int m0 = blockIdx.x * 128, n0 = blockIdx.y * 128;
  const int wr = w >> 1, wc = w & 1;
  const int fr = l & 15, fk = (l >> 4) * 8;

  f32x4 acc[4][4] = {};

  for (int k0 = 0; k0 < K; k0 += 32) {
    __syncthreads();
#pragma unroll
    for (int p = 0; p < 2; ++p) {
      int c = p * 256 + tid;
      int row = c >> 2, col = (c & 3) * 8;
      *(short8*)(&As[c * 8]) = *(const short8*)(&A[(size_t)(m0 + row) * K + k0 + col]);
      *(short8*)(&Bs[c * 8]) = *(const short8*)(&Bt[(size_t)(n0 + row) * K + k0 + col]);
    }
    __syncthreads();
    short8 af[4], bf[4];
#pragma unroll
    for (int mi = 0; mi < 4; ++mi) af[mi] = *(const short8*)(&As[(wr * 64 + mi * 16 + fr) * 32 + fk]);
#pragma unroll
    for (int ni = 0; ni < 4; ++ni) bf[ni] = *(const short8*)(&Bs[(wc * 64 + ni * 16 + fr) * 32 + fk]);
#pragma unroll
    for (int mi = 0; mi < 4; ++mi)
#pragma unroll
      for (int ni = 0; ni < 4; ++ni)
        acc[mi][ni] = MFMA_BF16(af[mi], bf[ni], acc[mi][ni]);
  }

#pragma unroll
  for (int ni = 0; ni < 4; ++ni) {
    int col = n0 + wc * 64 + ni * 16 + fr;
    int hh = col >> 6, dd = col & 63;
    float bv = bias[col];
#pragma unroll
    for (int mi = 0; mi < 4; ++mi) {
#pragma unroll
      for (int q = 0; q < 4; ++q) {
        int t = m0 + wr * 64 + mi * 16 + (l >> 4) * 4 + q;
        rhp[((unsigned)hh * 1152 + 64 + t) * 64 + dd] = f2bf(acc[mi][ni][q] + bv);
      }
    }
  }
}

// ---------------- fused rel-shift attention v4b: static-max softmax, single-buffer ----------------
// Static max (SMAX=20): P = exp(s-20); exp(m-20) cancels exactly in o/s. No per-tile
// row-max/row-sum shuffle reduces (~32 DS ops/tile removed); s_run per-lane, reduced once
// in epilogue. R9's 2-stage prefetch removed: it cost ~144 VGPRs -> scratch spills
// (WRITE_SIZE 53MB). Single named register set, plain loop.
__global__ __launch_bounds__(256, 2)
void attn_kernel(const ushort_t* __restrict__ qrw, const ushort_t* __restrict__ qrr,
                 const ushort_t* __restrict__ kb, const ushort_t* __restrict__ vt,
                 const ushort_t* __restrict__ rhp, ushort_t* __restrict__ ctx) {
  __shared__ __attribute__((aligned(16))) char PtB[4][2048];  // [16][64] bf16 per wave, swizzled

  const int tid = threadIdx.x, w = tid >> 6, l = tid & 63;
  const int bid = blockIdx.x;
  const int g = bid & 63;
  const int h = ((g & 7) << 1) | ((g >> 3) & 1);   // bid%8 fixes the head-pair (XCD L2 locality)
  const int b = g >> 4;
  const int bh = b * 16 + h;
  const int sx = 15 - (bid >> 6);                  // reversed: big strips first
  const int istrip = sx * 64 + w * 16;             // this wave's 16 q-rows
  const int fr = l & 15, fkq = (l >> 4) * 8;
  const float scale = 0.125f;
  char* Pw = PtB[w];

  // Q fragments in registers for the whole loop
  short8 aqw0, aqw1, aqr0, aqr1;
  {
    unsigned qb = ((unsigned)bh * T_LEN + istrip + fr) * 64 + fkq;
    aqw0 = *(const short8*)(qrw + qb);
    aqw1 = *(const short8*)(qrw + qb + 32);
    aqr0 = *(const short8*)(qrr + qb);
    aqr1 = *(const short8*)(qrr + qb + 32);
  }

  const unsigned kbase = ((unsigned)bh * T_LEN + fr) * 64 + fkq;
  const unsigned rbase = ((unsigned)h * 1152 + 64 + 1008 - istrip + fr) * 64 + fkq;
  const unsigned vbase = ((unsigned)bh * 64 + fr) * T_LEN + fkq;

  float s_run[4] = {0.f, 0.f, 0.f, 0.f};
  f32x4 o[4] = {};                                 // [d-group][q]

  const int njt = (istrip + 79) >> 6;              // 64-col tiles (per-wave causal bound)

  for (int jt = 0; jt < njt; ++jt) {
    const int j0 = jt << 6;

    // ---- K + R loads (single batch; one stall point) ----
    short8 kf[8], rf[10];
    {
      unsigned koff = kbase + (unsigned)j0 * 64;
#pragma unroll
      for (int f = 0; f < 4; ++f) {
        kf[2 * f] = *(const short8*)(kb + koff + f * 1024);
        kf[2 * f + 1] = *(const short8*)(kb + koff + f * 1024 + 32);
      }
      unsigned roff = rbase + (unsigned)j0 * 64;
#pragma unroll
      for (int f = 0; f < 5; ++f) {
        rf[2 * f] = *(const short8*)(rhp + roff + f * 1024);
        rf[2 * f + 1] = *(const short8*)(rhp + roff + f * 1024 + 32);
      }
    }

    // ---- AC / BD MFMA ----
    f32x4 ac[4] = {};
    f32x4 pb[5] = {};
#pragma unroll
    for (int f = 0; f < 4; ++f) {
      ac[f] = MFMA_BF16(aqw0, kf[2 * f], ac[f]);
      ac[f] = MFMA_BF16(aqw1, kf[2 * f + 1], ac[f]);
    }
#pragma unroll
    for (int f = 0; f < 5; ++f) {
      pb[f] = MFMA_BF16(aqr0, rf[2 * f], pb[f]);
      pb[f] = MFMA_BF16(aqr1, rf[2 * f + 1], pb[f]);
    }

    // ---- V loads issued before softmax (latency hides under it) ----
    short8 vf[8];
#pragma unroll
    for (int dg = 0; dg < 4; ++dg) {
      unsigned vb = vbase + (unsigned)(dg * 16384) + (unsigned)j0;
      vf[2 * dg] = *(const short8*)(vt + vb);
      vf[2 * dg + 1] = *(const short8*)(vt + vb + 32);
    }

    // ---- rel-shift gather + static-max softmax: P straight to LDS ----
#pragma unroll
    for (int q = 0; q < 4; ++q) {
      int ri = 4 * (l >> 4) + q;
      int e = 15 + fr - ri;                   // in [0,30]
      int src = (l & 48) | (e & 15);
      float sh[5];
#pragma unroll
      for (int f = 0; f < 5; ++f) sh[f] = __shfl(pb[f][q], src, 64);
      int hi = e >> 4;
      int ig = istrip + ri;
#pragma unroll
      for (int ni = 0; ni < 4; ++ni) {
        float pv = hi ? sh[ni + 1] : sh[ni];
        float s = (ac[ni][q] + pv) * scale - 20.0f;
        int jg = j0 + ni * 16 + fr;
        float p = (jg > ig) ? 0.f : __expf(s);
        *(ushort_t*)(Pw + (((ri * 128) + (ni * 16 + fr) * 2) ^ ((ri & 7) << 4))) = f2bf(p);
        s_run[q] += p;
      }
    }

    // ---- PV ----
    short8 pa0 = *(const short8*)(Pw + ((fr * 128 + fkq * 2) ^ ((fr & 7) << 4)));
    short8 pa1 = *(const short8*)(Pw + ((fr * 128 + 64 + fkq * 2) ^ ((fr & 7) << 4)));
#pragma unroll
    for (int dg = 0; dg < 4; ++dg) {
      o[dg] = MFMA_BF16(pa0, vf[2 * dg], o[dg]);
      o[dg] = MFMA_BF16(pa1, vf[2 * dg + 1], o[dg]);
    }
  }

  // ---- epilogue: one-time row-sum reduce, normalize, write ctx [T][B][E] bf16 ----
#pragma unroll
  for (int q = 0; q < 4; ++q) {
    float sq = s_run[q];
#pragma unroll
    for (int o2 = 8; o2; o2 >>= 1) sq += __shfl_xor(sq, o2, 64);
    s_run[q] = sq;
  }
#pragma unroll
  for (int dg = 0; dg < 4; ++dg) {
#pragma unroll
    for (int q = 0; q < 4; ++q) {
      int ig = istrip + 4 * (l >> 4) + q;
      int dd = dg * 16 + fr;
      float val = o[dg][q] / s_run[q];
      ctx[((size_t)ig * BATCH + b) * EMB + h * 64 + dd] = f2bf(val);
    }
  }
}

// ---------------- launch ----------------
extern "C" void kernel_launch(void* const* d_in, const int* in_sizes, int n_in,
                              void* d_out, int out_size, void* d_ws, size_t ws_size,
                              hipStream_t stream) {
  (void)in_sizes; (void)n_in; (void)out_size; (void)ws_size;
  const float* x = (const float*)d_in[0];
  const float* pos = (const float*)d_in[1];
  const float* in_w_mu = (const float*)d_in[3];
  const float* in_w_rho = (const float*)d_in[4];
  const float* in_w_eps = (const float*)d_in[5];
  const float* in_b_mu = (const float*)d_in[6];
  const float* in_b_rho = (const float*)d_in[7];
  const float* in_b_eps = (const float*)d_in[8];
  const float* pos_w_mu = (const float*)d_in[9];
  const float* pos_w_rho = (const float*)d_in[10];
  const float* pos_w_eps = (const float*)d_in[11];
  const float* pos_b_mu = (const float*)d_in[12];
  const float* pos_b_rho = (const float*)d_in[13];
  const float* pos_b_eps = (const float*)d_in[14];
  const float* out_w_mu = (const float*)d_in[15];
  const float* out_w_rho = (const float*)d_in[16];
  const float* out_w_eps = (const float*)d_in[17];
  const float* out_b_mu = (const float*)d_in[18];
  const float* out_b_rho = (const float*)d_in[19];
  const float* out_b_eps = (const float*)d_in[20];
  const float* rw_mu = (const float*)d_in[21];
  const float* rw_rho = (const float*)d_in[22];
  const float* rw_eps = (const float*)d_in[23];
  const float* rr_mu = (const float*)d_in[24];
  const float* rr_rho = (const float*)d_in[25];
  const float* rr_eps = (const float*)d_in[26];

  char* ws = (char*)d_ws;
  ushort_t* in_w_bf  = (ushort_t*)(ws + 0);          // 3072x1024 bf16
  ushort_t* pos_w_bf = (ushort_t*)(ws + 6291456);    // 1024x1024 bf16
  ushort_t* out_w_bf = (ushort_t*)(ws + 8388608);    // 1024x1024 bf16
  float* in_b  = (float*)(ws + 10485760);            // 3072
  float* pos_b = (float*)(ws + 10498048);            // 1024
  float* out_b = (float*)(ws + 10502144);            // 1024
  float* rwb   = (float*)(ws + 10506240);            // 1024
  float* rrb   = (float*)(ws + 10510336);            // 1024
  ushort_t* x_bf    = (ushort_t*)(ws + 10514432);    // 4096x1024 bf16
  ushort_t* posx_bf = (ushort_t*)(ws + 18903040);    // 1024x1024 bf16
  ushort_t* qrw = (ushort_t*)(ws + 21000192);        // [B][H][T][64] bf16
  ushort_t* qrr = (ushort_t*)(ws + 29388800);
  ushort_t* kb  = (ushort_t*)(ws + 37777408);
  ushort_t* vt  = (ushort_t*)(ws + 46166016);        // [B][H][64][T] bf16
  ushort_t* rhp = (ushort_t*)(ws + 54554624);        // [H][1152][64] bf16
  ushort_t* ctx = (ushort_t*)(ws + 56913920);        // [T][B][E] bf16

  sample_bf16_kernel<<<12288, 256, 0, stream>>>(in_w_mu, in_w_rho, in_w_eps, in_w_bf, 3145728);
  sample_bf16_kernel<<<4096, 256, 0, stream>>>(pos_w_mu, pos_w_rho, pos_w_eps, pos_w_bf, 1048576);
  sample_bf16_kernel<<<4096, 256, 0, stream>>>(out_w_mu, out_w_rho, out_w_eps, out_w_bf, 1048576);
  sample_f32_kernel<<<12, 256, 0, stream>>>(in_b_mu, in_b_rho, in_b_eps, in_b, 3072);
  sample_f32_kernel<<<4, 256, 0, stream>>>(pos_b_mu, pos_b_rho, pos_b_eps, pos_b, 1024);
  sample_f32_kernel<<<4, 256, 0, stream>>>(out_b_mu, out_b_rho, out_b_eps, out_b, 1024);
  sample_f32_kernel<<<4, 256, 0, stream>>>(rw_mu, rw_rho, rw_eps, rwb, 1024);
  sample_f32_kernel<<<4, 256, 0, stream>>>(rr_mu, rr_rho, rr_eps, rrb, 1024);
  cast_bf16_kernel<<<16384, 256, 0, stream>>>(x, x_bf, 4194304);
  cast_bf16_kernel<<<4096, 256, 0, stream>>>(pos, posx_bf, 1048576);
  zero_rhp_pad_kernel<<<512, 256, 0, stream>>>(rhp);

  gemm_qkv_fused_kernel<<<dim3(32, 24), 256, 0, stream>>>(x_bf, in_w_bf, in_b, rwb, rrb,
                                                          qrw, qrr, kb, vt);
  gemm_pos_fused_kernel<<<dim3(8, 8), 256, 0, stream>>>(posx_bf, pos_w_bf, pos_b, rhp);

  attn_kernel<<<dim3(1024), 256, 0, stream>>>(qrw, qrr, kb, vt, rhp, ctx);

  gemm_bt_kernel<<<dim3(32, 8), 256, 0, stream>>>(ctx, out_w_bf, out_b, (float*)d_out, 4096, 1024, 1024);
}

// Round 11
// 238.167 us; speedup vs baseline: 1.1875x; 1.1517x over previous
//
#include <hip/hip_runtime.h>

typedef unsigned short ushort_t;
typedef __attribute__((ext_vector_type(8))) short short8;
typedef __attribute__((ext_vector_type(4))) float f32x4;

#define MFMA_BF16(a, b, c) __builtin_amdgcn_mfma_f32_16x16x32_bf16((a), (b), (c), 0, 0, 0)

#define T_LEN 1024
#define BATCH 4
#define NHEAD 16
#define DHEAD 64
#define EMB 1024

__device__ __forceinline__ ushort_t f2bf(float f) {
  unsigned u = __float_as_uint(f);
  u += 0x7fffu + ((u >> 16) & 1u);
  return (ushort_t)(u >> 16);
}

// ---------------- elementwise ----------------
__global__ void sample_bf16_kernel(const float* __restrict__ mu, const float* __restrict__ rho,
                                   const float* __restrict__ eps, ushort_t* __restrict__ out, int n) {
  int i = blockIdx.x * 256 + threadIdx.x;
  if (i < n) {
    float sp = log1pf(__expf(rho[i]));
    out[i] = f2bf(mu[i] + sp * eps[i]);
  }
}

__global__ void sample_f32_kernel(const float* __restrict__ mu, const float* __restrict__ rho,
                                  const float* __restrict__ eps, float* __restrict__ out, int n) {
  int i = blockIdx.x * 256 + threadIdx.x;
  if (i < n) {
    float sp = log1pf(__expf(rho[i]));
    out[i] = mu[i] + sp * eps[i];
  }
}

__global__ void cast_bf16_kernel(const float* __restrict__ in, ushort_t* __restrict__ out, int n) {
  int i = blockIdx.x * 256 + threadIdx.x;
  if (i < n) out[i] = f2bf(in[i]);
}

// zero the rhp pad rows (phys rows 0..63 and 1088..1151 per head)
__global__ void zero_rhp_pad_kernel(ushort_t* __restrict__ rhp) {
  int idx = blockIdx.x * 256 + threadIdx.x;   // 16*128*64 = 131072
  int dd = idx & 63;
  int pr = (idx >> 6) & 127;
  int h = idx >> 13;
  int phys = (pr < 64) ? pr : (pr - 64 + 1088);
  rhp[((size_t)h * 1152 + phys) * 64 + dd] = 0;
}

// ---------------- GEMM: C[M][N] = A[M][K] * Bt[N][K]^T + bias[N] (f32 out) ----------------
__global__ __launch_bounds__(256, 2)
void gemm_bt_kernel(const ushort_t* __restrict__ A, const ushort_t* __restrict__ Bt,
                    const float* __restrict__ bias, float* __restrict__ C,
                    int M, int N, int K) {
  __shared__ ushort_t As[128 * 32];
  __shared__ ushort_t Bs[128 * 32];
  const int tid = threadIdx.x;
  const int w = tid >> 6, l = tid & 63;
  const int m0 = blockIdx.x * 128, n0 = blockIdx.y * 128;
  const int wr = w >> 1, wc = w & 1;
  const int fr = l & 15, fk = (l >> 4) * 8;

  f32x4 acc[4][4] = {};

  for (int k0 = 0; k0 < K; k0 += 32) {
    __syncthreads();
#pragma unroll
    for (int p = 0; p < 2; ++p) {
      int c = p * 256 + tid;
      int row = c >> 2, col = (c & 3) * 8;
      *(short8*)(&As[c * 8]) = *(const short8*)(&A[(size_t)(m0 + row) * K + k0 + col]);
      *(short8*)(&Bs[c * 8]) = *(const short8*)(&Bt[(size_t)(n0 + row) * K + k0 + col]);
    }
    __syncthreads();
    short8 af[4], bf[4];
#pragma unroll
    for (int mi = 0; mi < 4; ++mi) af[mi] = *(const short8*)(&As[(wr * 64 + mi * 16 + fr) * 32 + fk]);
#pragma unroll
    for (int ni = 0; ni < 4; ++ni) bf[ni] = *(const short8*)(&Bs[(wc * 64 + ni * 16 + fr) * 32 + fk]);
#pragma unroll
    for (int mi = 0; mi < 4; ++mi)
#pragma unroll
      for (int ni = 0; ni < 4; ++ni)
        acc[mi][ni] = MFMA_BF16(af[mi], bf[ni], acc[mi][ni]);
  }

#pragma unroll
  for (int ni = 0; ni < 4; ++ni) {
    int col = n0 + wc * 64 + ni * 16 + fr;
    float bv = bias[col];
#pragma unroll
    for (int mi = 0; mi < 4; ++mi) {
#pragma unroll
      for (int q = 0; q < 4; ++q) {
        int row = m0 + wr * 64 + mi * 16 + (l >> 4) * 4 + q;
        C[(size_t)row * N + col] = acc[mi][ni][q] + bv;
      }
    }
  }
}

// ---------------- fused QKV GEMM: epilogue writes qrw/qrr/kb/vt directly ----------------
__global__ __launch_bounds__(256, 2)
void gemm_qkv_fused_kernel(const ushort_t* __restrict__ A, const ushort_t* __restrict__ Bt,
                           const float* __restrict__ bias,
                           const float* __restrict__ rwb, const float* __restrict__ rrb,
                           ushort_t* __restrict__ qrw, ushort_t* __restrict__ qrr,
                           ushort_t* __restrict__ kbuf, ushort_t* __restrict__ vt) {
  __shared__ ushort_t As[128 * 32];
  __shared__ ushort_t Bs[128 * 32];
  const int K = 1024;
  const int tid = threadIdx.x;
  const int w = tid >> 6, l = tid & 63;
  const int m0 = blockIdx.x * 128, n0 = blockIdx.y * 128;
  const int wr = w >> 1, wc = w & 1;
  const int fr = l & 15, fk = (l >> 4) * 8;

  f32x4 acc[4][4] = {};

  for (int k0 = 0; k0 < K; k0 += 32) {
    __syncthreads();
#pragma unroll
    for (int p = 0; p < 2; ++p) {
      int c = p * 256 + tid;
      int row = c >> 2, col = (c & 3) * 8;
      *(short8*)(&As[c * 8]) = *(const short8*)(&A[(size_t)(m0 + row) * K + k0 + col]);
      *(short8*)(&Bs[c * 8]) = *(const short8*)(&Bt[(size_t)(n0 + row) * K + k0 + col]);
    }
    __syncthreads();
    short8 af[4], bf[4];
#pragma unroll
    for (int mi = 0; mi < 4; ++mi) af[mi] = *(const short8*)(&As[(wr * 64 + mi * 16 + fr) * 32 + fk]);
#pragma unroll
    for (int ni = 0; ni < 4; ++ni) bf[ni] = *(const short8*)(&Bs[(wc * 64 + ni * 16 + fr) * 32 + fk]);
#pragma unroll
    for (int mi = 0; mi < 4; ++mi)
#pragma unroll
      for (int ni = 0; ni < 4; ++ni)
        acc[mi][ni] = MFMA_BF16(af[mi], bf[ni], acc[mi][ni]);
  }

#pragma unroll
  for (int ni = 0; ni < 4; ++ni) {
    int col = n0 + wc * 64 + ni * 16 + fr;
    int part = col >> 10;
    int e = col & 1023;
    int hh = e >> 6, dd = e & 63;
    float bv = bias[col];
    float rwv = rwb[e];
    float rrv = rrb[e];
#pragma unroll
    for (int mi = 0; mi < 4; ++mi) {
#pragma unroll
      for (int q = 0; q < 4; ++q) {
        int row = m0 + wr * 64 + mi * 16 + (l >> 4) * 4 + q;
        int t = row >> 2, b = row & 3;
        float v = acc[mi][ni][q] + bv;
        if (part == 0) {
          unsigned idx = (((unsigned)(b * 16 + hh) * 1024 + t) << 6) + dd;
          qrw[idx] = f2bf(v + rwv);
          qrr[idx] = f2bf(v + rrv);
        } else if (part == 1) {
          unsigned idx = (((unsigned)(b * 16 + hh) * 1024 + t) << 6) + dd;
          kbuf[idx] = f2bf(v);
        } else {
          vt[(((unsigned)(b * 16 + hh) * 64 + dd) << 10) + t] = f2bf(v);
        }
      }
    }
  }
}

// ---------------- fused pos GEMM: epilogue writes rhp[h][64+t][dd] directly ----------------
__global__ __launch_bounds__(256, 2)
void gemm_pos_fused_kernel(const ushort_t* __restrict__ A, const ushort_t* __restrict__ Bt,
                           const float* __restrict__ bias, ushort_t* __restrict__ rhp) {
  __shared__ ushort_t As[128 * 32];
  __shared__ ushort_t Bs[128 * 32];
  const int K = 1024;
  const int tid = threadIdx.x;
  const int w = tid >> 6, l = tid & 63;
  const int m0 = blockIdx.x * 128, n0 = blockIdx.y * 128;
  const int wr = w >> 1, wc = w & 1;
  const int fr = l & 15, fk = (l >> 4) * 8;

  f32x4 acc[4][4] = {};

  for (int k0 = 0; k0 < K; k0 += 32) {
    __syncthreads();
#pragma unroll
    for (int p = 0; p < 2; ++p) {
      int c = p * 256 + tid;
      int row = c >> 2, col = (c & 3) * 8;
      *(short8*)(&As[c * 8]) = *(const short8*)(&A[(size_t)(m0 + row) * K + k0 + col]);
      *(short8*)(&Bs[c * 8]) = *(const short8*)(&Bt[(size_t)(n0 + row) * K + k0 + col]);
    }
    __syncthreads();
    short8 af[4], bf[4];
#pragma unroll
    for (int mi = 0; mi < 4; ++mi) af[mi] = *(const short8*)(&As[(wr * 64 + mi * 16 + fr) * 32 + fk]);
#pragma unroll
    for (int ni = 0; ni < 4; ++ni) bf[ni] = *(const short8*)(&Bs[(wc * 64 + ni * 16 + fr) * 32 + fk]);
#pragma unroll
    for (int mi = 0; mi < 4; ++mi)
#pragma unroll
      for (int ni = 0; ni < 4; ++ni)
        acc[mi][ni] = MFMA_BF16(af[mi], bf[ni], acc[mi][ni]);
  }

#pragma unroll
  for (int ni = 0; ni < 4; ++ni) {
    int col = n0 + wc * 64 + ni * 16 + fr;
    int hh = col >> 6, dd = col & 63;
    float bv = bias[col];
#pragma unroll
    for (int mi = 0; mi < 4; ++mi) {
#pragma unroll
      for (int q = 0; q < 4; ++q) {
        int t = m0 + wr * 64 + mi * 16 + (l >> 4) * 4 + q;
        rhp[((unsigned)hh * 1152 + 64 + t) * 64 + dd] = f2bf(acc[mi][ni][q] + bv);
      }
    }
  }
}

// ---------------- fused rel-shift attention v5: cooperative LDS K/V staging ----------------
// 4 waves/block share (bh, j-range): K+V 64x64 bf16 tiles staged cooperatively in LDS
// (reg-staged, double-buffered, XOR-swizzled byte ^= (row&7)<<4 on write AND read -> optimal
// b128 bank pattern). Stage loads for tile jt+1 issue BEFORE computing jt (T14): prefetch
// depth that cost 72 VGPRs in R9 now costs 16. K/V L2 traffic /4. R stays in regs (per-wave
// band). Static-max softmax (R10, validated). One barrier/tile; setprio around MFMA (T5).
__global__ __launch_bounds__(256, 2)
void attn_kernel(const ushort_t* __restrict__ qrw, const ushort_t* __restrict__ qrr,
                 const ushort_t* __restrict__ kb, const ushort_t* __restrict__ vt,
                 const ushort_t* __restrict__ rhp, ushort_t* __restrict__ ctx) {
  __shared__ __attribute__((aligned(16))) ushort_t KV[2][8192];  // [buf][K 8KB | V 8KB]
  __shared__ __attribute__((aligned(16))) char PtB[4][2048];     // per-wave P transpose

  const int tid = threadIdx.x, w = tid >> 6, l = tid & 63;
  const int bid = blockIdx.x;
  const int g = bid & 63;
  const int h = ((g & 7) << 1) | ((g >> 3) & 1);   // bid%8 fixes the head-pair (XCD L2 locality)
  const int b = g >> 4;
  const int bh = b * 16 + h;
  const int sx = 15 - (bid >> 6);                  // reversed: big strips first
  const int istrip = sx * 64 + w * 16;             // this wave's 16 q-rows
  const int fr = l & 15, fkq = (l >> 4) * 8;
  const float scale = 0.125f;
  char* Pw = PtB[w];
  const int njt = sx + 1;                          // uniform across the block's 4 waves

  // Q fragments in registers for the whole loop
  short8 aqw0, aqw1, aqr0, aqr1;
  {
    unsigned qb = ((unsigned)bh * T_LEN + istrip + fr) * 64 + fkq;
    aqw0 = *(const short8*)(qrw + qb);
    aqw1 = *(const short8*)(qrw + qb + 32);
    aqr0 = *(const short8*)(qrr + qb);
    aqr1 = *(const short8*)(qrr + qb + 32);
  }

  // staging geometry: wave w stages K rows [16w..16w+15] and V d-rows [16w..16w+15]
  const int srow = 16 * w + (l >> 3);                          // +8 for second load
  const unsigned sswz = (unsigned)(((l & 7) ^ (l >> 3)) << 4); // write-side swizzle (bytes)
  const unsigned kgcol = (unsigned)(l & 7) * 8;                // global col (elems)
  const unsigned swzr = (unsigned)(fr & 7) << 4;               // read-side swizzle (bytes)

  const unsigned rbase = ((unsigned)h * 1152 + 64 + 1008 - istrip + fr) * 64 + fkq;

  float s_run[4] = {0.f, 0.f, 0.f, 0.f};
  f32x4 o[4] = {};                                 // [d-group][q]

  short8 sg0, sg1, sg2, sg3;                       // staged K(2) + V(2) in-flight regs
#define STAGE_LOAD(J0)                                                              \
  do {                                                                              \
    sg0 = *(const short8*)(kb + ((unsigned)bh * 1024 + (unsigned)(J0) + srow) * 64 + kgcol);      \
    sg1 = *(const short8*)(kb + ((unsigned)bh * 1024 + (unsigned)(J0) + srow + 8) * 64 + kgcol);  \
    sg2 = *(const short8*)(vt + ((unsigned)bh * 64 + srow) * 1024 + (unsigned)(J0) + kgcol);      \
    sg3 = *(const short8*)(vt + ((unsigned)bh * 64 + srow + 8) * 1024 + (unsigned)(J0) + kgcol);  \
  } while (0)
#define STAGE_WRITE(BUF)                                                            \
  do {                                                                              \
    char* KS_ = (char*)KV[BUF];                                                     \
    *(short8*)(KS_ + (unsigned)srow * 128 + sswz) = sg0;                            \
    *(short8*)(KS_ + (unsigned)(srow + 8) * 128 + sswz) = sg1;                      \
    *(short8*)(KS_ + 8192 + (unsigned)srow * 128 + sswz) = sg2;                     \
    *(short8*)(KS_ + 8192 + (unsigned)(srow + 8) * 128 + sswz) = sg3;               \
  } while (0)

  // prologue: stage tile 0
  STAGE_LOAD(0);
  STAGE_WRITE(0);
  __syncthreads();

  for (int jt = 0; jt < njt; ++jt) {
    const int j0 = jt << 6;
    const char* KS = (const char*)KV[jt & 1];

    // ---- issue next tile's stage loads early (latency hides under this tile) ----
    if (jt + 1 < njt) STAGE_LOAD((jt + 1) << 6);

    // ---- R loads (global -> regs, per-wave band) ----
    short8 rf[10];
    {
      unsigned roff = rbase + (unsigned)j0 * 64;
#pragma unroll
      for (int f = 0; f < 5; ++f) {
        rf[2 * f] = *(const short8*)(rhp + roff + f * 1024);
        rf[2 * f + 1] = *(const short8*)(rhp + roff + f * 1024 + 32);
      }
    }

    // ---- K from LDS (swizzled), AC / BD MFMA ----
    f32x4 ac[4] = {};
    f32x4 pb[5] = {};
    {
      short8 kf[8];
#pragma unroll
      for (int f = 0; f < 4; ++f) {
        unsigned rowb = (unsigned)(f * 16 + fr) * 128;
        kf[2 * f] = *(const short8*)(KS + rowb + (((unsigned)fkq * 2) ^ swzr));
        kf[2 * f + 1] = *(const short8*)(KS + rowb + (((unsigned)fkq * 2 + 64) ^ swzr));
      }
      __builtin_amdgcn_s_setprio(1);
#pragma unroll
      for (int f = 0; f < 4; ++f) {
        ac[f] = MFMA_BF16(aqw0, kf[2 * f], ac[f]);
        ac[f] = MFMA_BF16(aqw1, kf[2 * f + 1], ac[f]);
      }
#pragma unroll
      for (int f = 0; f < 5; ++f) {
        pb[f] = MFMA_BF16(aqr0, rf[2 * f], pb[f]);
        pb[f] = MFMA_BF16(aqr1, rf[2 * f + 1], pb[f]);
      }
      __builtin_amdgcn_s_setprio(0);
    }

    // ---- V from LDS (swizzled) -- issue before softmax so lgkm overlaps ----
    short8 vf[8];
#pragma unroll
    for (int dg = 0; dg < 4; ++dg) {
      unsigned rowb = 8192 + (unsigned)(dg * 16 + fr) * 128;
      vf[2 * dg] = *(const short8*)(KS + rowb + (((unsigned)fkq * 2) ^ swzr));
      vf[2 * dg + 1] = *(const short8*)(KS + rowb + (((unsigned)(64 + fkq * 2)) ^ swzr));
    }

    // ---- rel-shift gather + static-max softmax: P straight to LDS ----
#pragma unroll
    for (int q = 0; q < 4; ++q) {
      int ri = 4 * (l >> 4) + q;
      int e = 15 + fr - ri;                   // in [0,30]
      int src = (l & 48) | (e & 15);
      float sh[5];
#pragma unroll
      for (int f = 0; f < 5; ++f) sh[f] = __shfl(pb[f][q], src, 64);
      int hi = e >> 4;
      int ig = istrip + ri;
#pragma unroll
      for (int ni = 0; ni < 4; ++ni) {
        float pv = hi ? sh[ni + 1] : sh[ni];
        float s = (ac[ni][q] + pv) * scale - 20.0f;
        int jg = j0 + ni * 16 + fr;
        float p = (jg > ig) ? 0.f : __expf(s);
        *(ushort_t*)(Pw + (((ri * 128) + (ni * 16 + fr) * 2) ^ ((ri & 7) << 4))) = f2bf(p);
        s_run[q] += p;
      }
    }

    // ---- PV ----
    {
      short8 pa0 = *(const short8*)(Pw + ((fr * 128 + fkq * 2) ^ ((fr & 7) << 4)));
      short8 pa1 = *(const short8*)(Pw + ((fr * 128 + 64 + fkq * 2) ^ ((fr & 7) << 4)));
      __builtin_amdgcn_s_setprio(1);
#pragma unroll
      for (int dg = 0; dg < 4; ++dg) {
        o[dg] = MFMA_BF16(pa0, vf[2 * dg], o[dg]);
        o[dg] = MFMA_BF16(pa1, vf[2 * dg + 1], o[dg]);
      }
      __builtin_amdgcn_s_setprio(0);
    }

    // ---- write staged regs into the other buffer, then sync ----
    if (jt + 1 < njt) STAGE_WRITE((jt + 1) & 1);
    __syncthreads();
  }

  // ---- epilogue: one-time row-sum reduce, normalize, write ctx [T][B][E] bf16 ----
#pragma unroll
  for (int q = 0; q < 4; ++q) {
    float sq = s_run[q];
#pragma unroll
    for (int o2 = 8; o2; o2 >>= 1) sq += __shfl_xor(sq, o2, 64);
    s_run[q] = sq;
  }
#pragma unroll
  for (int dg = 0; dg < 4; ++dg) {
#pragma unroll
    for (int q = 0; q < 4; ++q) {
      int ig = istrip + 4 * (l >> 4) + q;
      int dd = dg * 16 + fr;
      float val = o[dg][q] / s_run[q];
      ctx[((size_t)ig * BATCH + b) * EMB + h * 64 + dd] = f2bf(val);
    }
  }
}

// ---------------- launch ----------------
extern "C" void kernel_launch(void* const* d_in, const int* in_sizes, int n_in,
                              void* d_out, int out_size, void* d_ws, size_t ws_size,
                              hipStream_t stream) {
  (void)in_sizes; (void)n_in; (void)out_size; (void)ws_size;
  const float* x = (const float*)d_in[0];
  const float* pos = (const float*)d_in[1];
  const float* in_w_mu = (const float*)d_in[3];
  const float* in_w_rho = (const float*)d_in[4];
  const float* in_w_eps = (const float*)d_in[5];
  const float* in_b_mu = (const float*)d_in[6];
  const float* in_b_rho = (const float*)d_in[7];
  const float* in_b_eps = (const float*)d_in[8];
  const float* pos_w_mu = (const float*)d_in[9];
  const float* pos_w_rho = (const float*)d_in[10];
  const float* pos_w_eps = (const float*)d_in[11];
  const float* pos_b_mu = (const float*)d_in[12];
  const float* pos_b_rho = (const float*)d_in[13];
  const float* pos_b_eps = (const float*)d_in[14];
  const float* out_w_mu = (const float*)d_in[15];
  const float* out_w_rho = (const float*)d_in[16];
  const float* out_w_eps = (const float*)d_in[17];
  const float* out_b_mu = (const float*)d_in[18];
  const float* out_b_rho = (const float*)d_in[19];
  const float* out_b_eps = (const float*)d_in[20];
  const float* rw_mu = (const float*)d_in[21];
  const float* rw_rho = (const float*)d_in[22];
  const float* rw_eps = (const float*)d_in[23];
  const float* rr_mu = (const float*)d_in[24];
  const float* rr_rho = (const float*)d_in[25];
  const float* rr_eps = (const float*)d_in[26];

  char* ws = (char*)d_ws;
  ushort_t* in_w_bf  = (ushort_t*)(ws + 0);          // 3072x1024 bf16
  ushort_t* pos_w_bf = (ushort_t*)(ws + 6291456);    // 1024x1024 bf16
  ushort_t* out_w_bf = (ushort_t*)(ws + 8388608);    // 1024x1024 bf16
  float* in_b  = (float*)(ws + 10485760);            // 3072
  float* pos_b = (float*)(ws + 10498048);            // 1024
  float* out_b = (float*)(ws + 10502144);            // 1024
  float* rwb   = (float*)(ws + 10506240);            // 1024
  float* rrb   = (float*)(ws + 10510336);            // 1024
  ushort_t* x_bf    = (ushort_t*)(ws + 10514432);    // 4096x1024 bf16
  ushort_t* posx_bf = (ushort_t*)(ws + 18903040);    // 1024x1024 bf16
  ushort_t* qrw = (ushort_t*)(ws + 21000192);        // [B][H][T][64] bf16
  ushort_t* qrr = (ushort_t*)(ws + 29388800);
  ushort_t* kb  = (ushort_t*)(ws + 37777408);
  ushort_t* vt  = (ushort_t*)(ws + 46166016);        // [B][H][64][T] bf16
  ushort_t* rhp = (ushort_t*)(ws + 54554624);        // [H][1152][64] bf16
  ushort_t* ctx = (ushort_t*)(ws + 56913920);        // [T][B][E] bf16

  sample_bf16_kernel<<<12288, 256, 0, stream>>>(in_w_mu, in_w_rho, in_w_eps, in_w_bf, 3145728);
  sample_bf16_kernel<<<4096, 256, 0, stream>>>(pos_w_mu, pos_w_rho, pos_w_eps, pos_w_bf, 1048576);
  sample_bf16_kernel<<<4096, 256, 0, stream>>>(out_w_mu, out_w_rho, out_w_eps, out_w_bf, 1048576);
  sample_f32_kernel<<<12, 256, 0, stream>>>(in_b_mu, in_b_rho, in_b_eps, in_b, 3072);
  sample_f32_kernel<<<4, 256, 0, stream>>>(pos_b_mu, pos_b_rho, pos_b_eps, pos_b, 1024);
  sample_f32_kernel<<<4, 256, 0, stream>>>(out_b_mu, out_b_rho, out_b_eps, out_b, 1024);
  sample_f32_kernel<<<4, 256, 0, stream>>>(rw_mu, rw_rho, rw_eps, rwb, 1024);
  sample_f32_kernel<<<4, 256, 0, stream>>>(rr_mu, rr_rho, rr_eps, rrb, 1024);
  cast_bf16_kernel<<<16384, 256, 0, stream>>>(x, x_bf, 4194304);
  cast_bf16_kernel<<<4096, 256, 0, stream>>>(pos, posx_bf, 1048576);
  zero_rhp_pad_kernel<<<512, 256, 0, stream>>>(rhp);

  gemm_qkv_fused_kernel<<<dim3(32, 24), 256, 0, stream>>>(x_bf, in_w_bf, in_b, rwb, rrb,
                                                          qrw, qrr, kb, vt);
  gemm_pos_fused_kernel<<<dim3(8, 8), 256, 0, stream>>>(posx_bf, pos_w_bf, pos_b, rhp);

  attn_kernel<<<dim3(1024), 256, 0, stream>>>(qrw, qrr, kb, vt, rhp, ctx);

  gemm_bt_kernel<<<dim3(32, 8), 256, 0, stream>>>(ctx, out_w_bf, out_b, (float*)d_out, 4096, 1024, 1024);
}